// Round 1
// baseline (80.622 us; speedup 1.0000x reference)
//
#include <hip/hip_runtime.h>

#define PN 131072
#define PH 1024

// Pack per-hidden-unit params into float4 for a single uniform 16B load per h:
// pk[h] = (W1[h,0], W1[h,1], b1[h], w2[h])
__global__ __launch_bounds__(256) void prep_kernel(const float* __restrict__ W1,
                                                   const float* __restrict__ b1,
                                                   const float* __restrict__ w2,
                                                   float4* __restrict__ pk) {
    int h = blockIdx.x * blockDim.x + threadIdx.x;
    if (h < PH) {
        pk[h] = make_float4(W1[2 * h], W1[2 * h + 1], b1[h], w2[h]);
    }
}

__global__ __launch_bounds__(256) void pde_kernel(const float* __restrict__ x,
                                                  const float4* __restrict__ pk,
                                                  const float* __restrict__ b2p,
                                                  float* __restrict__ out) {
    const int i = blockIdx.x * blockDim.x + threadIdx.x;
    const float2 xv = reinterpret_cast<const float2*>(x)[i];
    const float x0 = xv.x;
    const float x1 = xv.y;

    float acc_out  = 0.0f;  // sum t*w2
    float acc_dt   = 0.0f;  // sum s*W1[:,0]
    float acc_dx   = 0.0f;  // sum s*W1[:,1]
    float acc_dxdx = 0.0f;  // sum t*s*W1[:,1]^2   (df_dxdx = -2 * this)

    #pragma unroll 8
    for (int h = 0; h < PH; ++h) {
        const float4 p = pk[h];          // wave-uniform -> scalar load
        const float w10 = p.x, w11 = p.y, b1h = p.z, w2h = p.w;

        const float z = __builtin_fmaf(x0, w10, __builtin_fmaf(x1, w11, b1h));
        // tanh(z) = 1 - 2/(exp(2z)+1); exp(2z) = 2^(z * 2*log2(e))
        const float e = __builtin_amdgcn_exp2f(z * 2.8853900817779268f);
        const float r = __builtin_amdgcn_rcpf(e + 1.0f);
        const float t = __builtin_fmaf(-2.0f, r, 1.0f);

        acc_out = __builtin_fmaf(t, w2h, acc_out);
        const float s = __builtin_fmaf(-t * t, w2h, w2h);   // (1 - t^2) * w2h
        acc_dt = __builtin_fmaf(s, w10, acc_dt);
        acc_dx = __builtin_fmaf(s, w11, acc_dx);
        const float ts = t * s;
        acc_dxdx = __builtin_fmaf(ts * w11, w11, acc_dxdx);
    }

    const float b2 = b2p[0];
    const float output = acc_out + b2;
    const float df_dxdx = -2.0f * acc_dxdx;
    // pde = 0.5*x1^2 + df_dt + 0.5*sigma^2*df_dxdx + 0.5*x1*df_dx - c^2/(4*c_f)*df_dx^2
    const float pde = __builtin_fmaf(0.5f * x1, x1, acc_dt)
                    + 0.5f * df_dxdx
                    + 0.5f * x1 * acc_dx
                    - 0.069444444444444445f * acc_dx * acc_dx;

    out[i] = output;
    out[PN + i] = pde;
}

extern "C" void kernel_launch(void* const* d_in, const int* in_sizes, int n_in,
                              void* d_out, int out_size, void* d_ws, size_t ws_size,
                              hipStream_t stream) {
    const float* x  = (const float*)d_in[0];
    const float* W1 = (const float*)d_in[1];
    const float* b1 = (const float*)d_in[2];
    const float* w2 = (const float*)d_in[3];
    const float* b2 = (const float*)d_in[4];
    float* out = (float*)d_out;
    float4* pk = (float4*)d_ws;

    prep_kernel<<<PH / 256, 256, 0, stream>>>(W1, b1, w2, pk);
    pde_kernel<<<PN / 256, 256, 0, stream>>>(x, pk, b2, out);
}

// Round 2
// 58.974 us; speedup vs baseline: 1.3671x; 1.3671x over previous
//
#include <hip/hip_runtime.h>

#define PN 131072
#define PH 1024
#define SPLIT 4
#define CH (PH / SPLIT)   // 256 h-iterations per wave

// pk[2h]   = (w10*2log2e, w11*2log2e, b1*2log2e, w2)
// pk[2h+1] = (w10*w2, w11*w2, w11^2*w2, 0)
__global__ __launch_bounds__(256) void prep_kernel(const float* __restrict__ W1,
                                                   const float* __restrict__ b1,
                                                   const float* __restrict__ w2,
                                                   float4* __restrict__ pk) {
    int h = blockIdx.x * blockDim.x + threadIdx.x;
    if (h < PH) {
        const float SC = 2.8853900817779268f;  // 2*log2(e)
        float w10 = W1[2 * h], w11 = W1[2 * h + 1], w2h = w2[h];
        pk[2 * h]     = make_float4(w10 * SC, w11 * SC, b1[h] * SC, w2h);
        pk[2 * h + 1] = make_float4(w10 * w2h, w11 * w2h, w11 * w11 * w2h, 0.0f);
    }
}

__global__ __launch_bounds__(256, 8) void pde_kernel(const float* __restrict__ x,
                                                     const float4* __restrict__ pk,
                                                     const float* __restrict__ b2p,
                                                     float* __restrict__ out) {
    const int lane = threadIdx.x & 63;
    const int wv   = threadIdx.x >> 6;                       // 0..3, for LDS indexing
    const int wvu  = __builtin_amdgcn_readfirstlane(wv);     // SGPR -> scalar loads
    const int row  = blockIdx.x * 64 + lane;

    const float2 xv = reinterpret_cast<const float2*>(x)[row];
    const float x0 = xv.x;
    const float x1 = xv.y;

    const float4* __restrict__ p = pk + (size_t)wvu * (2 * CH);

    float acc_out  = 0.0f;  // sum t*w2
    float acc_dt   = 0.0f;  // sum q*(w10*w2)
    float acc_dx   = 0.0f;  // sum q*(w11*w2)
    float acc_dxdx = 0.0f;  // sum t*q*(w11^2*w2)

    #pragma unroll 8
    for (int it = 0; it < CH; ++it) {
        const float4 a  = p[2 * it];       // scaled weights + w2
        const float4 pr = p[2 * it + 1];   // premultiplied products

        const float zs = __builtin_fmaf(x0, a.x, __builtin_fmaf(x1, a.y, a.z));
        const float e  = __builtin_amdgcn_exp2f(zs);       // exp(2z)
        const float r  = __builtin_amdgcn_rcpf(e + 1.0f);  // 1/(e^{2z}+1)
        const float t  = __builtin_fmaf(-2.0f, r, 1.0f);   // tanh(z)
        const float q  = __builtin_fmaf(-t, t, 1.0f);      // 1 - t^2
        const float tq = t * q;

        acc_out  = __builtin_fmaf(t,  a.w,  acc_out);
        acc_dt   = __builtin_fmaf(q,  pr.x, acc_dt);
        acc_dx   = __builtin_fmaf(q,  pr.y, acc_dx);
        acc_dxdx = __builtin_fmaf(tq, pr.z, acc_dxdx);
    }

    // Cross-wave reduction: 4 waves each hold partial sums for the same 64 rows.
    __shared__ float4 red[4][64];
    if (wv != 0) {
        red[wv][lane] = make_float4(acc_out, acc_dt, acc_dx, acc_dxdx);
    }
    __syncthreads();
    if (wv == 0) {
        #pragma unroll
        for (int w = 1; w < SPLIT; ++w) {
            const float4 o = red[w][lane];
            acc_out  += o.x;
            acc_dt   += o.y;
            acc_dx   += o.z;
            acc_dxdx += o.w;
        }
        const float b2 = b2p[0];
        const float output  = acc_out + b2;
        const float df_dxdx = -2.0f * acc_dxdx;
        const float pde = __builtin_fmaf(0.5f * x1, x1, acc_dt)
                        + 0.5f * df_dxdx
                        + 0.5f * x1 * acc_dx
                        - 0.069444444444444445f * acc_dx * acc_dx;
        out[row] = output;
        out[PN + row] = pde;
    }
}

extern "C" void kernel_launch(void* const* d_in, const int* in_sizes, int n_in,
                              void* d_out, int out_size, void* d_ws, size_t ws_size,
                              hipStream_t stream) {
    const float* x  = (const float*)d_in[0];
    const float* W1 = (const float*)d_in[1];
    const float* b1 = (const float*)d_in[2];
    const float* w2 = (const float*)d_in[3];
    const float* b2 = (const float*)d_in[4];
    float* out = (float*)d_out;
    float4* pk = (float4*)d_ws;   // 1024 * 32 B = 32 KiB

    prep_kernel<<<PH / 256, 256, 0, stream>>>(W1, b1, w2, pk);
    pde_kernel<<<PN / 64, 256, 0, stream>>>(x, pk, b2, out);
}